// Round 1
// baseline (1396.608 us; speedup 1.0000x reference)
//
#include <hip/hip_runtime.h>

#define BB 32
#define DIM 4096
#define NH 32
#define NKV 8
#define HD 128
#define KVLEN 4096
#define QKVC 6144  // DIM + 2*NKV*HD
#define GQ 4
#define QKV_SPLITS 32
#define WO_SPLITS 32

// ---------------- kernel A: xqkv partials = x @ wqkv (K-split, NO atomics) -----
__global__ __launch_bounds__(256, 4) void k_qkv(const float* __restrict__ x,
                                                const float* __restrict__ w,
                                                float* __restrict__ part) {
    int j  = blockIdx.x * 256 + threadIdx.x;          // column 0..6143 (24 blocks)
    int d0 = blockIdx.y * (DIM / QKV_SPLITS);         // 128 rows per split
    float acc[BB];
#pragma unroll
    for (int b = 0; b < BB; ++b) acc[b] = 0.f;
    for (int dd = d0; dd < d0 + DIM / QKV_SPLITS; dd += 8) {
        float wr[8];
#pragma unroll
        for (int k = 0; k < 8; ++k) wr[k] = w[(size_t)(dd + k) * QKVC + j];
#pragma unroll
        for (int b = 0; b < BB; ++b) {
            float4 xa = *(const float4*)&x[b * DIM + dd];      // wave-uniform
            float4 xb = *(const float4*)&x[b * DIM + dd + 4];
            float t = acc[b];
            t = fmaf(xa.x, wr[0], t); t = fmaf(xa.y, wr[1], t);
            t = fmaf(xa.z, wr[2], t); t = fmaf(xa.w, wr[3], t);
            t = fmaf(xb.x, wr[4], t); t = fmaf(xb.y, wr[5], t);
            t = fmaf(xb.z, wr[6], t); t = fmaf(xb.w, wr[7], t);
            acc[b] = t;
        }
    }
#pragma unroll
    for (int b = 0; b < BB; ++b)
        part[(size_t)blockIdx.y * (BB * QKVC) + (size_t)b * QKVC + j] = acc[b];
}

// ---------------- generic split reduction: dst = sum_p src[p] ------------------
__global__ __launch_bounds__(256) void k_red(const float* __restrict__ src,
                                             float* __restrict__ dst,
                                             int parts, int n4) {
    int i = blockIdx.x * 256 + threadIdx.x;
    if (i >= n4) return;
    const float4* s4 = (const float4*)src;
    float4 a = s4[i];
    for (int p = 1; p < parts; ++p) {
        float4 b = s4[(size_t)p * n4 + i];
        a.x += b.x; a.y += b.y; a.z += b.z; a.w += b.w;
    }
    ((float4*)dst)[i] = a;
}

// ---------------- kernel R: rotary for q,k; cache update; v passthrough --------
__global__ __launch_bounds__(128) void k_rot(const float* __restrict__ xqkv,
                                             const float* __restrict__ rot,
                                             const int* __restrict__ curpos,
                                             float* __restrict__ qws,
                                             float* __restrict__ ck,
                                             float* __restrict__ cv) {
    int c  = blockIdx.x;    // 0..47: 0-31 q heads, 32-39 k heads, 40-47 v heads
    int b  = blockIdx.y;    // batch
    int dp = threadIdx.x;   // 0..127 output dim
    int pos = *curpos;
    const float* row = &xqkv[(size_t)b * QKVC + c * HD];
    if (c < 40) {
        float acc = 0.f;
#pragma unroll 4
        for (int d = 0; d < HD; ++d) acc = fmaf(row[d], rot[d * HD + dp], acc);
        if (c < 32) {
            qws[((size_t)b * NH + c) * HD + dp] = acc;
        } else {
            int kvh = c - 32;
            ck[(((size_t)b * NKV + kvh) * KVLEN + pos) * HD + dp] = acc;
        }
    } else {
        int kvh = c - 40;
        cv[(((size_t)b * NKV + kvh) * KVLEN + pos) * HD + dp] = row[dp];
    }
}

// ---------------- kernel B1: scores = QK^T*scale + mask, online (m,l) ----------
// Register prefetch (T14): issue tile t+1's global loads under tile t's compute.
__global__ __launch_bounds__(256, 4) void k_qk(const float* __restrict__ ck,
                                               const float* __restrict__ qws,
                                               const float* __restrict__ mask,
                                               const int* __restrict__ curpos,
                                               float* __restrict__ scores,
                                               float2* __restrict__ stats) {
    __shared__ float Kl[64 * 132];   // 64 keys x 128 dims, stride 132 (pad)
    __shared__ float ql[4 * 128];    // 4 heads of q
    int bkv = blockIdx.x;            // 0..255
    int split = blockIdx.y;          // 0..3 (1024 keys each)
    int b = bkv >> 3, kv = bkv & 7;
    int tid = threadIdx.x;
    int g = tid >> 6, lane = tid & 63;   // wave = head
    int pos = *curpos;
    int L = min((((pos + 1) + 31) >> 5) << 5, KVLEN);

    for (int i = tid; i < GQ * HD; i += 256)
        ql[i] = qws[((size_t)b * NH + kv * GQ) * HD + i];

    const float scale = 0.08838834764831845f;  // 1/sqrt(128)
    float m = -3.0e38f, lsum = 0.f;
    int l0 = split * 1024;
    int h = kv * GQ + g;

    const float4* Kbase = (const float4*)&ck[((size_t)bkv * KVLEN + l0) * HD];
    float4 kreg[8];
#pragma unroll
    for (int i = 0; i < 8; ++i) kreg[i] = Kbase[i * 256 + tid];   // tile 0

    for (int t = 0; t < 16; ++t) {
#pragma unroll
        for (int i = 0; i < 8; ++i) {
            int c4i = i * 256 + tid;
            int row = c4i >> 5, c4 = c4i & 31;
            *(float4*)&Kl[row * 132 + c4 * 4] = kreg[i];
        }
        __syncthreads();                       // also covers ql on t==0
        if (t < 15) {
            const float4* Kn = Kbase + (size_t)(t + 1) * 2048;
#pragma unroll
            for (int i = 0; i < 8; ++i) kreg[i] = Kn[i * 256 + tid];  // prefetch
        }
        float s = 0.f;
#pragma unroll
        for (int d4 = 0; d4 < 32; ++d4) {
            float4 kk = *(const float4*)&Kl[lane * 132 + d4 * 4];
            float4 qq = *(const float4*)&ql[g * HD + d4 * 4];
            s += kk.x * qq.x + kk.y * qq.y + kk.z * qq.z + kk.w * qq.w;
        }
        int l = l0 + t * 64 + lane;
        s = s * scale + mask[((size_t)h * BB + b) * KVLEN + l];
        if (l >= L) {
            s = -3.0e38f;
        } else {
            if (s > m) { lsum = lsum * __expf(m - s) + 1.f; m = s; }
            else       { lsum += __expf(s - m); }
        }
        scores[((size_t)(bkv * GQ + g)) * KVLEN + l] = s;
        __syncthreads();
    }
    // wave reduce (m, lsum) over 64 lanes
#pragma unroll
    for (int off = 32; off > 0; off >>= 1) {
        float mo = __shfl_xor(m, off);
        float lo = __shfl_xor(lsum, off);
        float M2 = fmaxf(m, mo);
        lsum = lsum * __expf(m - M2) + lo * __expf(mo - M2);
        m = M2;
    }
    if (lane == 0) stats[(bkv * GQ + g) * 4 + split] = make_float2(m, lsum);
}

// ---------------- kernel S: merge split stats -> (M, 1/L) ----------------------
__global__ void k_stats(const float2* __restrict__ stats, float2* __restrict__ mfin) {
    int i = blockIdx.x * 256 + threadIdx.x;  // 0..1023 = (bkv*4+g)
    if (i >= BB * NKV * GQ) return;
    float m = -3.0e38f, l = 0.f;
#pragma unroll
    for (int s = 0; s < 4; ++s) {
        float2 p = stats[i * 4 + s];
        float M2 = fmaxf(m, p.x);
        l = l * __expf(m - M2) + p.y * __expf(p.x - M2);
        m = M2;
    }
    mfin[i] = make_float2(m, l > 0.f ? 1.f / l : 0.f);
}

// ---------------- kernel B2: attn partials = P @ V (4-way KV split) ------------
// float4 V loads, probabilities recomputed in-register (scores chunk is L1-hot),
// no LDS in the hot loop; LDS only for the final 16-group tree reduce.
__global__ __launch_bounds__(512, 6) void k_pv(const float* __restrict__ cv,
                                               const float* __restrict__ scores,
                                               const float2* __restrict__ mfin,
                                               float* __restrict__ attn_part) {
    int bkv = blockIdx.x;            // 0..255
    int split = blockIdx.y;          // 0..3
    int tid = threadIdx.x;
    int d4 = tid & 31;               // float4 slot within the 128-dim row
    int lg = tid >> 5;               // 0..15 key-groups of 64 keys
    int l0 = split * 1024 + lg * 64;

    float2 ML[GQ];
#pragma unroll
    for (int g = 0; g < GQ; ++g) ML[g] = mfin[bkv * GQ + g];

    float4 acc[GQ];
#pragma unroll
    for (int g = 0; g < GQ; ++g) acc[g] = make_float4(0.f, 0.f, 0.f, 0.f);

    const float* Vg = &cv[((size_t)bkv * KVLEN + l0) * HD + d4 * 4];
    const float* Sg = &scores[(size_t)bkv * GQ * KVLEN + l0];

#pragma unroll 4
    for (int i = 0; i < 64; ++i) {
        float4 v = *(const float4*)&Vg[(size_t)i * HD];
#pragma unroll
        for (int g = 0; g < GQ; ++g) {
            float s = Sg[(size_t)g * KVLEN + i];           // 2 addrs/wave, L1 broadcast
            float p = __expf(s - ML[g].x) * ML[g].y;       // masked s=-3e38 -> p=0
            acc[g].x = fmaf(p, v.x, acc[g].x);
            acc[g].y = fmaf(p, v.y, acc[g].y);
            acc[g].z = fmaf(p, v.z, acc[g].z);
            acc[g].w = fmaf(p, v.w, acc[g].w);
        }
    }

    __shared__ float red[16][GQ][HD];   // 32 KB
#pragma unroll
    for (int g = 0; g < GQ; ++g) *(float4*)&red[lg][g][d4 * 4] = acc[g];
    __syncthreads();
    {   // 512 threads: one (g,d) output each, sum over 16 key-groups
        int g2 = tid >> 7, d = tid & 127;
        float o = 0.f;
#pragma unroll
        for (int k = 0; k < 16; ++k) o += red[k][g2][d];
        int b = bkv >> 3, kv = bkv & 7;
        attn_part[(size_t)split * (BB * DIM) + (size_t)b * DIM + (kv * GQ + g2) * HD + d] = o;
    }
}

// ---------------- kernel C: out partials = attn @ wo (K-split, NO atomics) -----
__global__ __launch_bounds__(256, 4) void k_wo(const float* __restrict__ attn,
                                               const float* __restrict__ wo,
                                               float* __restrict__ part) {
    int j  = blockIdx.x * 256 + threadIdx.x;       // 0..4095 (16 blocks)
    int d0 = blockIdx.y * (DIM / WO_SPLITS);       // 128 rows per split
    float acc[BB];
#pragma unroll
    for (int b = 0; b < BB; ++b) acc[b] = 0.f;
    for (int dd = d0; dd < d0 + DIM / WO_SPLITS; dd += 8) {
        float wr[8];
#pragma unroll
        for (int k = 0; k < 8; ++k) wr[k] = wo[(size_t)(dd + k) * DIM + j];
#pragma unroll
        for (int b = 0; b < BB; ++b) {
            float4 xa = *(const float4*)&attn[b * DIM + dd];   // wave-uniform
            float4 xb = *(const float4*)&attn[b * DIM + dd + 4];
            float t = acc[b];
            t = fmaf(xa.x, wr[0], t); t = fmaf(xa.y, wr[1], t);
            t = fmaf(xa.z, wr[2], t); t = fmaf(xa.w, wr[3], t);
            t = fmaf(xb.x, wr[4], t); t = fmaf(xb.y, wr[5], t);
            t = fmaf(xb.z, wr[6], t); t = fmaf(xb.w, wr[7], t);
            acc[b] = t;
        }
    }
#pragma unroll
    for (int b = 0; b < BB; ++b)
        part[(size_t)blockIdx.y * (BB * DIM) + (size_t)b * DIM + j] = acc[b];
}

extern "C" void kernel_launch(void* const* d_in, const int* in_sizes, int n_in,
                              void* d_out, int out_size, void* d_ws, size_t ws_size,
                              hipStream_t stream) {
    const float* x    = (const float*)d_in[0];
    const float* wqkv = (const float*)d_in[1];
    const float* wo   = (const float*)d_in[2];
    const float* rot  = (const float*)d_in[3];
    float* ck         = (float*)d_in[4];   // mutated: row current_pos (restored by harness)
    float* cv         = (float*)d_in[5];
    const float* mask = (const float*)d_in[6];
    const int* curpos = (const int*)d_in[7];
    float* out        = (float*)d_out;

    char* ws = (char*)d_ws;
    float*  xqkv_part = (float*)(ws);                   // 32*32*6144*4 = 25,165,824
    float*  xqkv      = (float*)(ws + 25165824);        // 786,432
    float*  qws       = (float*)(ws + 25952256);        // 524,288
    float*  scores    = (float*)(ws + 26476544);        // 16,777,216
    float2* stats     = (float2*)(ws + 43253760);       // 32,768
    float2* mfin      = (float2*)(ws + 43286528);       // 8,192
    float*  attn_part = (float*)(ws + 43294720);        // 4*524288 = 2,097,152
    float*  attn      = (float*)(ws + 45391872);        // 524,288
    float*  out_part  = (float*)(ws + 45916160);        // 32*524288 = 16,777,216
    // total ws used ~62.7 MB

    k_qkv  <<<dim3(QKVC / 256, QKV_SPLITS), 256, 0, stream>>>(x, wqkv, xqkv_part);
    k_red  <<<dim3(192),                    256, 0, stream>>>(xqkv_part, xqkv, QKV_SPLITS, BB * QKVC / 4);
    k_rot  <<<dim3(48, BB),                 128, 0, stream>>>(xqkv, rot, curpos, qws, ck, cv);
    k_qk   <<<dim3(BB * NKV, 4),            256, 0, stream>>>(ck, qws, mask, curpos, scores, stats);
    k_stats<<<dim3(4),                      256, 0, stream>>>(stats, mfin);
    k_pv   <<<dim3(BB * NKV, 4),            512, 0, stream>>>(cv, scores, mfin, attn_part);
    k_red  <<<dim3(128),                    256, 0, stream>>>(attn_part, attn, 4, BB * DIM / 4);
    k_wo   <<<dim3(DIM / 256, WO_SPLITS),   256, 0, stream>>>(attn, wo, out_part);
    k_red  <<<dim3(128),                    256, 0, stream>>>(out_part, out, WO_SPLITS, BB * DIM / 4);
}